// Round 15
// baseline (345.022 us; speedup 1.0000x reference)
//
#include <hip/hip_runtime.h>
#include <math.h>

#define N1 961
#define N2 960
#define KF 240
#define HW2 3844   // 62*62
#define NPIX 15376 // 4*62*62
#define XDSZ 492032 // 4*128*961
#define L2E 1.44269504f

__global__ void k_zero(float* p, int n) {
  int i = blockIdx.x * 256 + threadIdx.x;
  if (i < n) p[i] = 0.f;
}

// down conv v4: 2x2 px x 4 co per thread, K-split x8 (1024 blocks = 4/CU).
__global__ __launch_bounds__(256) void k_down(const float* __restrict__ x,
                                              const float* __restrict__ w,
                                              float* __restrict__ p0, float* __restrict__ p1,
                                              float* __restrict__ p2, float* __restrict__ p3,
                                              float* __restrict__ p4, float* __restrict__ p5,
                                              float* __restrict__ p6, float* __restrict__ p7) {
  __shared__ float iS[4][18][72];
  __shared__ float wS[4][16][16];  // [ci][tap][co16]
  int tid = threadIdx.x;
  int bid = blockIdx.x;
  int kchunk = bid & 7;
  int rowtile = (bid >> 3) & 3;
  int cog = (bid >> 5) & 7;
  int b = bid >> 8;
  int r0 = rowtile * 8;
  int wv = tid >> 6, lane = tid & 63;
  int pc = lane & 15, pr = lane >> 4;
  float acc[4][4];  // [px][co]
  #pragma unroll
  for (int i = 0; i < 4; i++)
    #pragma unroll
    for (int j = 0; j < 4; j++) acc[i][j] = 0.f;
  const float* xb = x + (size_t)b * 64 * 4096;
  for (int sub = 0; sub < 2; sub++) {
    int cibase = kchunk * 8 + sub * 4;
    __syncthreads();
    for (int e = tid; e < 4 * 18 * 66; e += 256) {
      int dx = e % 66; int t = e / 66;
      int dy = t % 18; int ci = t / 18;
      int iy = 2 * r0 + dy;
      iS[ci][dy][dx] = (dx < 64 && iy < 64)
                           ? xb[(size_t)(cibase + ci) * 4096 + iy * 64 + dx] : 0.f;
    }
    for (int e = tid; e < 1024; e += 256) {
      int co = e & 15, tap = (e >> 4) & 15, ci = e >> 8;
      wS[ci][tap][co] = w[(size_t)(cog * 16 + co) * 1024 + (cibase + ci) * 16 + tap];
    }
    __syncthreads();
    #pragma unroll
    for (int ci = 0; ci < 4; ci++) {
      float xr[6][6];
      #pragma unroll
      for (int rr = 0; rr < 6; rr++)
        #pragma unroll
        for (int jj = 0; jj < 3; jj++) {
          float2 v2 = *(const float2*)&iS[ci][4 * pr + rr][4 * pc + 2 * jj];
          xr[rr][2 * jj] = v2.x; xr[rr][2 * jj + 1] = v2.y;
        }
      #pragma unroll
      for (int ky = 0; ky < 4; ky++)
        #pragma unroll
        for (int kx = 0; kx < 4; kx++) {
          float4 wq = *(const float4*)&wS[ci][ky * 4 + kx][wv * 4];  // broadcast
          #pragma unroll
          for (int dy2 = 0; dy2 < 2; dy2++)
            #pragma unroll
            for (int dx2 = 0; dx2 < 2; dx2++) {
              float xv = xr[2 * dy2 + ky][2 * dx2 + kx];
              int px = dy2 * 2 + dx2;
              acc[px][0] += wq.x * xv; acc[px][1] += wq.y * xv;
              acc[px][2] += wq.z * xv; acc[px][3] += wq.w * xv;
            }
        }
    }
  }
  float* parts[8] = {p0, p1, p2, p3, p4, p5, p6, p7};
  float* xo = parts[kchunk] + (size_t)b * 128 * N1;
  #pragma unroll
  for (int dy2 = 0; dy2 < 2; dy2++) {
    int r = r0 + 2 * pr + dy2;
    if (r >= 31) continue;
    #pragma unroll
    for (int dx2 = 0; dx2 < 2; dx2++) {
      int c = 2 * pc + dx2;
      if (c >= 31) continue;
      #pragma unroll
      for (int cc = 0; cc < 4; cc++)
        xo[(size_t)(cog * 16 + wv * 4 + cc) * N1 + r * 31 + c] = acc[dy2 * 2 + dx2][cc];
    }
  }
}

// combine 7 K-partials + xd(8th partial) + bias -> xd
__global__ __launch_bounds__(256) void k_combine(const float* __restrict__ p0,
                                                 const float* __restrict__ p1,
                                                 const float* __restrict__ p2,
                                                 const float* __restrict__ p3,
                                                 const float* __restrict__ p4,
                                                 const float* __restrict__ p5,
                                                 const float* __restrict__ p6,
                                                 const float* __restrict__ bias,
                                                 float* __restrict__ xd) {
  int i = blockIdx.x * 256 + threadIdx.x;
  if (i >= XDSZ) return;
  int co = (i / N1) & 127;
  float s = ((p0[i] + p1[i]) + (p2[i] + p3[i])) + ((p4[i] + p5[i]) + (p6[i] + xd[i]));
  xd[i] = bias[co] + s;
}

#define QKV_EXPR(off) make_float4( \
    t0 * Ws[(off)] + t1 * Ws[12 + (off)] + t2 * Ws[24 + (off)] + t3 * Ws[36 + (off)] + Bs[(off)], \
    t0 * Ws[(off)+1] + t1 * Ws[12 + (off)+1] + t2 * Ws[24 + (off)+1] + t3 * Ws[36 + (off)+1] + Bs[(off)+1], \
    t0 * Ws[(off)+2] + t1 * Ws[12 + (off)+2] + t2 * Ws[24 + (off)+2] + t3 * Ws[36 + (off)+2] + Bs[(off)+2], \
    t0 * Ws[(off)+3] + t1 * Ws[12 + (off)+3] + t2 * Ws[24 + (off)+3] + t3 * Ws[36 + (off)+3] + Bs[(off)+3])

// load qkv weights; q-columns (0..3) pre-scaled by log2(e) so exp(s) == exp2(k.q')
#define LOAD_W_SCALED(wqkv, bqkv) do { \
    if (tid < 48) { float wv_ = (wqkv)[tid]; if ((tid % 12) < 4) wv_ *= L2E; Ws[tid] = wv_; } \
    if (tid < 12) { float bv_ = (bqkv)[tid]; if (tid < 4) bv_ *= L2E; Bs[tid] = bv_; } \
  } while (0)

// attention 1: 2 rows/thread, 8-way m-octants. grid = 128 bg x 16 chunks of 64 rows.
// wave = 8 rows x 8 octants, thread rows (n0, n0+8); shfl_xor(8,16,32) combine.
__global__ __launch_bounds__(256) void k_attn1(const float* __restrict__ xd,
                                               const float* __restrict__ wqkv,
                                               const float* __restrict__ bqkv,
                                               float* __restrict__ o1,
                                               float* __restrict__ rowstat) {
  __shared__ float4 qvv[2 * N1];
  __shared__ float Ws[48], Bs[12];
  int tid = threadIdx.x;
  int chunk = blockIdx.x & 15;
  int bg = blockIdx.x >> 4;
  int b = bg >> 5, g = bg & 31;
  LOAD_W_SCALED(wqkv, bqkv);
  __syncthreads();
  const float* xp0 = xd + (size_t)(b * 128 + g * 4) * N1;
  for (int nn = tid; nn < N1; nn += 256) {
    float t0 = xp0[nn], t1 = xp0[N1 + nn], t2 = xp0[2 * N1 + nn], t3 = xp0[3 * N1 + nn];
    qvv[2 * nn]     = QKV_EXPR(0);
    qvv[2 * nn + 1] = QKV_EXPR(8);
  }
  __syncthreads();
  int wv = tid >> 6, lane = tid & 63;
  int oc = lane >> 3;
  int n0 = chunk * 64 + wv * 16 + (lane & 7);
  if (n0 >= N1) return;  // all octant-partners share n0 -> exit together
  int n1 = n0 + 8;
  bool v1 = n1 < N1;
  int n1c = v1 ? n1 : n0;
  float t0 = xp0[n0], t1 = xp0[N1 + n0], t2 = xp0[2 * N1 + n0], t3 = xp0[3 * N1 + n0];
  float4 kr0 = QKV_EXPR(4);
  t0 = xp0[n1c]; t1 = xp0[N1 + n1c]; t2 = xp0[2 * N1 + n1c]; t3 = xp0[3 * N1 + n1c];
  float4 kr1 = QKV_EXPR(4);
  int ns = oc * 121;
  int ne = (ns + 121 < N1) ? ns + 121 : N1;
  float sum0 = 0.f, a00 = 0.f, a01 = 0.f, a02 = 0.f, a03 = 0.f;
  float sum1 = 0.f, a10 = 0.f, a11 = 0.f, a12 = 0.f, a13 = 0.f;
  #pragma unroll 4
  for (int m = ns; m < ne; m++) {
    float4 q = qvv[2 * m];
    float4 v = qvv[2 * m + 1];
    float s0 = kr0.x * q.x + kr0.y * q.y + kr0.z * q.z + kr0.w * q.w;
    float s1 = kr1.x * q.x + kr1.y * q.y + kr1.z * q.z + kr1.w * q.w;
    float e0 = __builtin_amdgcn_exp2f(s0);
    float e1 = __builtin_amdgcn_exp2f(s1);
    sum0 += e0; a00 += e0 * v.x; a01 += e0 * v.y; a02 += e0 * v.z; a03 += e0 * v.w;
    sum1 += e1; a10 += e1 * v.x; a11 += e1 * v.y; a12 += e1 * v.z; a13 += e1 * v.w;
  }
  #pragma unroll
  for (int off = 8; off <= 32; off <<= 1) {
    sum0 += __shfl_xor(sum0, off, 64); a00 += __shfl_xor(a00, off, 64);
    a01 += __shfl_xor(a01, off, 64);   a02 += __shfl_xor(a02, off, 64);
    a03 += __shfl_xor(a03, off, 64);
    sum1 += __shfl_xor(sum1, off, 64); a10 += __shfl_xor(a10, off, 64);
    a11 += __shfl_xor(a11, off, 64);   a12 += __shfl_xor(a12, off, 64);
    a13 += __shfl_xor(a13, off, 64);
  }
  if (oc != 0) return;
  float* o1p = o1 + (size_t)(b * 128 + g * 4) * N1;
  float inv0 = 1.0f / sum0;
  o1p[n0] = a00 * inv0;
  o1p[N1 + n0] = a01 * inv0;
  o1p[2 * N1 + n0] = a02 * inv0;
  o1p[3 * N1 + n0] = a03 * inv0;
  if (g < 16) rowstat[(size_t)(b * 16 + g) * N1 + n0] = inv0;
  if (v1) {
    float inv1 = 1.0f / sum1;
    o1p[n1] = a10 * inv1;
    o1p[N1 + n1] = a11 * inv1;
    o1p[2 * N1 + n1] = a12 * inv1;
    o1p[3 * N1 + n1] = a13 * inv1;
    if (g < 16) rowstat[(size_t)(b * 16 + g) * N1 + n1] = inv1;
  }
}

// coarse: 2 cols/thread, 16-way n-segments. grid = 64 bg x 32 chunks of 32 cols.
// wave = 4 cols x 16 segments, thread cols (m0, m0+4); shfl_xor(4,8,16,32).
__global__ __launch_bounds__(256) void k_coarse(const float* __restrict__ xd,
                                                const float* __restrict__ wqkv,
                                                const float* __restrict__ bqkv,
                                                const float* __restrict__ rowstat,
                                                float* __restrict__ coarse) {
  __shared__ float4 kS[N1];
  __shared__ float rs[N1];
  __shared__ float Ws[48], Bs[12];
  int tid = threadIdx.x;
  int chunk = blockIdx.x & 31;
  int bg = blockIdx.x >> 5;
  int b = bg >> 4, g = bg & 15;
  LOAD_W_SCALED(wqkv, bqkv);
  __syncthreads();
  const float* xp0 = xd + (size_t)(b * 128 + g * 4) * N1;
  const float* rp = rowstat + (size_t)(b * 16 + g) * N1;
  for (int nn = tid; nn < N1; nn += 256) {
    float t0 = xp0[nn], t1 = xp0[N1 + nn], t2 = xp0[2 * N1 + nn], t3 = xp0[3 * N1 + nn];
    kS[nn] = QKV_EXPR(4);
    rs[nn] = rp[nn];
  }
  __syncthreads();
  int wv = tid >> 6, lane = tid & 63;
  int sx = lane >> 2;
  int m0 = chunk * 32 + wv * 8 + (lane & 3);
  if (m0 >= N1) return;  // segment partners share m0 -> exit together
  int m1 = m0 + 4;
  bool v1 = m1 < N1;
  int m1c = v1 ? m1 : m0;
  float t0 = xp0[m0], t1 = xp0[N1 + m0], t2 = xp0[2 * N1 + m0], t3 = xp0[3 * N1 + m0];
  float4 q0 = QKV_EXPR(0);  // pre-scaled by log2e
  t0 = xp0[m1c]; t1 = xp0[N1 + m1c]; t2 = xp0[2 * N1 + m1c]; t3 = xp0[3 * N1 + m1c];
  float4 q1 = QKV_EXPR(0);
  int ns = sx * 61;
  int ne = (ns + 61 < N1) ? ns + 61 : N1;
  float c0 = 0.f, c1 = 0.f;
  #pragma unroll 4
  for (int n = ns; n < ne; n++) {
    float4 k = kS[n];
    float r = rs[n];
    float s0 = k.x * q0.x + k.y * q0.y + k.z * q0.z + k.w * q0.w;
    float s1 = k.x * q1.x + k.y * q1.y + k.z * q1.z + k.w * q1.w;
    c0 += __builtin_amdgcn_exp2f(s0) * r;
    c1 += __builtin_amdgcn_exp2f(s1) * r;
  }
  #pragma unroll
  for (int off = 4; off <= 32; off <<= 1) {
    c0 += __shfl_xor(c0, off, 64);
    c1 += __shfl_xor(c1, off, 64);
  }
  if (sx != 0) return;
  coarse[(size_t)(b * 16 + g) * N1 + m0] = c0;
  if (v1) coarse[(size_t)(b * 16 + g) * N1 + m1] = c1;
}

// top-240 per (b,g<16): bitonic over 1024 packed keys
__global__ __launch_bounds__(256) void k_topk(const float* __restrict__ coarse,
                                              int* __restrict__ topk) {
  __shared__ unsigned long long keys[1024];
  int tid = threadIdx.x;
  int bg = blockIdx.x;
  const float* cp = coarse + (size_t)bg * N1;
  for (int i = tid; i < 1024; i += 256) {
    unsigned long long key = 0ull;
    if (i < N1) {
      unsigned fb = __float_as_uint(cp[i]);
      key = ((unsigned long long)fb << 32) | (unsigned)(N1 - 1 - i);
    }
    keys[i] = key;
  }
  __syncthreads();
  for (int k2 = 2; k2 <= 1024; k2 <<= 1) {
    for (int j = k2 >> 1; j > 0; j >>= 1) {
      for (int i = tid; i < 1024; i += 256) {
        int ixj = i ^ j;
        if (ixj > i) {
          unsigned long long a = keys[i], bb = keys[ixj];
          bool up = ((i & k2) == 0);
          if ((a > bb) == up) { keys[i] = bb; keys[ixj] = a; }
        }
      }
      __syncthreads();
    }
  }
  if (tid < KF) {
    unsigned long long key = keys[1023 - tid];
    topk[(size_t)bg * KF + tid] = (N1 - 1) - (int)(unsigned)(key & 0xffffffffull);
  }
}

// transposed conv, per-parity: o1(4,128,31,31) -> yacc = 2*coarse_out (4,64,62,62)
__global__ __launch_bounds__(256) void k_upconv(const float* __restrict__ o1,
                                                const float* __restrict__ w,
                                                const float* __restrict__ bias,
                                                float* __restrict__ yacc) {
  __shared__ float iS[16][9][12];
  __shared__ float wS[16][4][16];  // [ci][tap][co16]
  int tid = threadIdx.x;
  int bid = blockIdx.x;
  int b = bid >> 8;
  int cog = (bid >> 6) & 3;
  int par = (bid >> 4) & 3;
  int py = par >> 1, px = par & 1;
  int tile = bid & 15;
  int r0 = (tile >> 2) * 8, c0 = (tile & 3) * 8;
  int wv = tid >> 6, lane = tid & 63;
  int pr = lane >> 3, pc = lane & 7;
  int cobase = cog * 16 + wv * 4;
  int wo[4];
  #pragma unroll
  for (int t = 0; t < 4; t++) {
    int a = t >> 1, d = t & 1;
    wo[t] = (3 - (py + 2 * a)) * 4 + (3 - (px + 2 * d));
  }
  float acc[4] = {0.f, 0.f, 0.f, 0.f};
  const float* ob = o1 + (size_t)b * 128 * N1;
  for (int ch = 0; ch < 8; ch++) {
    __syncthreads();
    for (int e = tid; e < 16 * 81; e += 256) {
      int dx = e % 9; int t = e / 9;
      int dy = t % 9; int ci = t / 9;
      int iy = r0 + py - 1 + dy, ix = c0 + px - 1 + dx;
      float v = 0.f;
      if (iy >= 0 && iy < 31 && ix >= 0 && ix < 31)
        v = ob[(size_t)(ch * 16 + ci) * N1 + iy * 31 + ix];
      iS[ci][dy][dx] = v;
    }
    for (int e = tid; e < 1024; e += 256) {
      int co = e & 15, tap = (e >> 4) & 3, ci = e >> 6;
      wS[ci][tap][co] = w[(size_t)(ch * 16 + ci) * 1024 + (cog * 16 + co) * 16 + wo[tap]];
    }
    __syncthreads();
    #pragma unroll
    for (int ci = 0; ci < 16; ci++) {
      float xr[2][2];
      #pragma unroll
      for (int a = 0; a < 2; a++) {
        xr[a][0] = iS[ci][pr + a][pc];
        xr[a][1] = iS[ci][pr + a][pc + 1];
      }
      #pragma unroll
      for (int t = 0; t < 4; t++) {
        float4 wq = *(const float4*)&wS[ci][t][wv * 4];  // broadcast
        float xv = xr[t >> 1][t & 1];
        acc[0] += wq.x * xv; acc[1] += wq.y * xv;
        acc[2] += wq.z * xv; acc[3] += wq.w * xv;
      }
    }
  }
  int r = r0 + pr, c = c0 + pc;
  if (r >= 31 || c >= 31) return;
  int y = 2 * r + py, xx = 2 * c + px;
  #pragma unroll
  for (int cc = 0; cc < 4; cc++) {
    int co = cobase + cc;
    yacc[(size_t)(b * 64 + co) * HW2 + y * 62 + xx] = 2.0f * (acc[cc] + bias[co]);
  }
}

// attention 2: 2 rows/thread, 8-way m-octants. grid = 64 bg x 15 chunks of 64 rows.
__global__ __launch_bounds__(256) void k_attn2(const float* __restrict__ yacc,
                                               const float* __restrict__ wqkv,
                                               const float* __restrict__ bqkv,
                                               const int* __restrict__ topk,
                                               float4* __restrict__ o2,
                                               int* __restrict__ coordg) {
  __shared__ float4 qvv[2 * N2];
  __shared__ float Ws[48], Bs[12];
  int tid = threadIdx.x;
  int chunk = blockIdx.x % 15;
  int bg = blockIdx.x / 15;
  int b = bg >> 4, g = bg & 15;
  LOAD_W_SCALED(wqkv, bqkv);
  __syncthreads();
  const float* yp0 = yacc + (size_t)(b * 64 + g * 4) * HW2;
  const int* ip = topk + (size_t)bg * KF;
  for (int nn = tid; nn < N2; nn += 256) {
    int tt = nn >> 2, i = (nn >> 1) & 1, j = nn & 1;
    int p = ip[tt];
    int ph = p / 31, pw = p - ph * 31;
    int cc = (2 * ph + i) * 62 + (2 * pw + j);
    float t0 = 0.5f * yp0[cc], t1 = 0.5f * yp0[HW2 + cc];
    float t2 = 0.5f * yp0[2 * HW2 + cc], t3 = 0.5f * yp0[3 * HW2 + cc];
    qvv[2 * nn]     = QKV_EXPR(0);
    qvv[2 * nn + 1] = QKV_EXPR(8);
  }
  __syncthreads();
  int wv = tid >> 6, lane = tid & 63;
  int oc = lane >> 3;
  int n0 = chunk * 64 + wv * 16 + (lane & 7);
  int n1 = n0 + 8;
  bool v1 = n1 < N2;
  int n1c = v1 ? n1 : n0;
  int tt = n0 >> 2, i = (n0 >> 1) & 1, j = n0 & 1;
  int p = ip[tt];
  int ph = p / 31, pw = p - ph * 31;
  int cc0 = (2 * ph + i) * 62 + (2 * pw + j);
  float t0 = 0.5f * yp0[cc0], t1 = 0.5f * yp0[HW2 + cc0];
  float t2 = 0.5f * yp0[2 * HW2 + cc0], t3 = 0.5f * yp0[3 * HW2 + cc0];
  float4 kr0 = QKV_EXPR(4);
  tt = n1c >> 2; i = (n1c >> 1) & 1; j = n1c & 1;
  p = ip[tt];
  ph = p / 31; pw = p - ph * 31;
  int cc1 = (2 * ph + i) * 62 + (2 * pw + j);
  t0 = 0.5f * yp0[cc1]; t1 = 0.5f * yp0[HW2 + cc1];
  t2 = 0.5f * yp0[2 * HW2 + cc1]; t3 = 0.5f * yp0[3 * HW2 + cc1];
  float4 kr1 = QKV_EXPR(4);
  int ns = oc * 120;
  int ne = ns + 120;
  float sum0 = 0.f, a00 = 0.f, a01 = 0.f, a02 = 0.f, a03 = 0.f;
  float sum1 = 0.f, a10 = 0.f, a11 = 0.f, a12 = 0.f, a13 = 0.f;
  #pragma unroll 4
  for (int m = ns; m < ne; m++) {
    float4 q = qvv[2 * m];
    float4 v = qvv[2 * m + 1];
    float s0 = kr0.x * q.x + kr0.y * q.y + kr0.z * q.z + kr0.w * q.w;
    float s1 = kr1.x * q.x + kr1.y * q.y + kr1.z * q.z + kr1.w * q.w;
    float e0 = __builtin_amdgcn_exp2f(s0);
    float e1 = __builtin_amdgcn_exp2f(s1);
    sum0 += e0; a00 += e0 * v.x; a01 += e0 * v.y; a02 += e0 * v.z; a03 += e0 * v.w;
    sum1 += e1; a10 += e1 * v.x; a11 += e1 * v.y; a12 += e1 * v.z; a13 += e1 * v.w;
  }
  #pragma unroll
  for (int off = 8; off <= 32; off <<= 1) {
    sum0 += __shfl_xor(sum0, off, 64); a00 += __shfl_xor(a00, off, 64);
    a01 += __shfl_xor(a01, off, 64);   a02 += __shfl_xor(a02, off, 64);
    a03 += __shfl_xor(a03, off, 64);
    sum1 += __shfl_xor(sum1, off, 64); a10 += __shfl_xor(a10, off, 64);
    a11 += __shfl_xor(a11, off, 64);   a12 += __shfl_xor(a12, off, 64);
    a13 += __shfl_xor(a13, off, 64);
  }
  if (oc != 0) return;
  float inv0 = 1.0f / sum0;
  size_t oi = (size_t)bg * N2 + n0;
  o2[oi] = make_float4(a00 * inv0, a01 * inv0, a02 * inv0, a03 * inv0);
  coordg[oi] = cc0;
  if (v1) {
    float inv1 = 1.0f / sum1;
    oi = (size_t)bg * N2 + n1;
    o2[oi] = make_float4(a10 * inv1, a11 * inv1, a12 * inv1, a13 * inv1);
    coordg[oi] = cc1;
  }
}

// scatter-add attn2 output into yacc (disjoint targets)
__global__ __launch_bounds__(256) void k_scatter(float* __restrict__ yacc,
                                                 const float4* __restrict__ o2,
                                                 const int* __restrict__ coordg) {
  int idx = blockIdx.x * 256 + threadIdx.x;
  if (idx >= 64 * N2) return;
  int bg = idx / N2;
  int b = bg >> 4, g = bg & 15;
  float4 o = o2[idx];
  int cc = coordg[idx];
  float* yp0 = yacc + (size_t)(b * 64 + g * 4) * HW2;
  yp0[cc] += o.x;
  yp0[HW2 + cc] += o.y;
  yp0[2 * HW2 + cc] += o.z;
  yp0[3 * HW2 + cc] += o.w;
}

// depthwise 3x3, pad 1
__global__ __launch_bounds__(256) void k_dwconv(const float* __restrict__ yin,
                                                const float* __restrict__ w,
                                                float* __restrict__ z1) {
  int idx = blockIdx.x * 256 + threadIdx.x;
  if (idx >= 64 * NPIX) return;
  int x = idx % 62; int t = idx / 62;
  int y = t % 62; t /= 62;
  int c = t % 64;
  int plane = idx / HW2;
  const float* yp = yin + (size_t)plane * HW2;
  const float* wp = w + c * 9;
  float acc = 0.f;
  #pragma unroll
  for (int ky = 0; ky < 3; ky++) {
    int yy = y + ky - 1;
    if (yy < 0 || yy > 61) continue;
    #pragma unroll
    for (int kx = 0; kx < 3; kx++) {
      int xx = x + kx - 1;
      if (xx < 0 || xx > 61) continue;
      acc += yp[yy * 62 + xx] * wp[ky * 3 + kx];
    }
  }
  z1[idx] = acc;
}

__device__ __forceinline__ float wave_sum(float x) {
  #pragma unroll
  for (int off = 32; off > 0; off >>= 1) x += __shfl_xor(x, off, 64);
  return x;
}

// per-channel sum/sumsq; grid 1024 = c(64) x b(4) x seg(4: 961 px each; 4*961==HW2)
__global__ __launch_bounds__(256) void k_stats(const float* __restrict__ buf,
                                               float* __restrict__ stats) {
  __shared__ float red[8];
  int bid = blockIdx.x;
  int seg = bid & 3;
  int b = (bid >> 2) & 3;
  int c = bid >> 4;
  const float* p = buf + (size_t)(b * 64 + c) * HW2;
  int i0 = seg * 961;
  float s = 0.f, s2 = 0.f;
  for (int i = i0 + threadIdx.x; i < i0 + 961; i += 256) {
    float z = p[i]; s += z; s2 += z * z;
  }
  s = wave_sum(s); s2 = wave_sum(s2);
  int wave = threadIdx.x >> 6, lane = threadIdx.x & 63;
  if (lane == 0) { red[wave] = s; red[4 + wave] = s2; }
  __syncthreads();
  if (threadIdx.x == 0) {
    atomicAdd(&stats[c], red[0] + red[1] + red[2] + red[3]);
    atomicAdd(&stats[64 + c], red[4] + red[5] + red[6] + red[7]);
  }
}

__global__ void k_bnparam(const float* __restrict__ stats, const float* __restrict__ gamma,
                          const float* __restrict__ beta, float* __restrict__ par) {
  int c = threadIdx.x;
  if (c < 64) {
    float m = stats[c] * (1.0f / NPIX);
    float v = stats[64 + c] * (1.0f / NPIX) - m * m;
    float a = gamma[c] * rsqrtf(v + 1e-5f);
    par[c] = a; par[64 + c] = beta[c] - m * a;
  }
}

// pointwise 1x1, co-split x16 (4 co/block): grid = pixblocks(61) x cog(16)
__global__ __launch_bounds__(256) void k_pwconv(const float* __restrict__ z1,
                                                const float* __restrict__ wpw,
                                                const float* __restrict__ par,
                                                float* __restrict__ z2) {
  __shared__ float w[4 * 64];
  __shared__ float aa[64], cb[64];
  int tid = threadIdx.x;
  int cog = blockIdx.x & 15;
  int pb = blockIdx.x >> 4;
  if (tid < 64) { aa[tid] = par[tid]; cb[tid] = par[64 + tid]; }
  for (int i = tid; i < 256; i += 256) w[i] = wpw[cog * 256 + i];
  __syncthreads();
  int pix = pb * 256 + tid;
  if (pix >= NPIX) return;
  int b = pix / HW2, p = pix - b * HW2;
  float h[64];
  #pragma unroll
  for (int ci = 0; ci < 64; ci++) {
    float z = z1[(size_t)(b * 64 + ci) * HW2 + p];
    z = aa[ci] * z + cb[ci];
    h[ci] = fminf(fmaxf(z, 0.f), 6.f);
  }
  #pragma unroll
  for (int cc = 0; cc < 4; cc++) {
    float acc = 0.f;
    #pragma unroll
    for (int ci = 0; ci < 64; ci++) acc += h[ci] * w[cc * 64 + ci];
    z2[(size_t)(b * 64 + cog * 4 + cc) * HW2 + p] = acc;
  }
}

__global__ __launch_bounds__(256) void k_final(const float* __restrict__ z2,
                                               const float* __restrict__ par,
                                               float* __restrict__ out) {
  int idx = blockIdx.x * 256 + threadIdx.x;
  if (idx >= 64 * NPIX) return;
  int c = (idx / HW2) & 63;
  float z = par[c] * z2[idx] + par[64 + c];
  out[idx] = fminf(fmaxf(z, 0.f), 6.f);
}

extern "C" void kernel_launch(void* const* d_in, const int* in_sizes, int n_in,
                              void* d_out, int out_size, void* d_ws, size_t ws_size,
                              hipStream_t stream) {
  const float* x       = (const float*)d_in[0];
  const float* w_down  = (const float*)d_in[1];
  const float* b_down  = (const float*)d_in[2];
  const float* w_qkv_c = (const float*)d_in[3];
  const float* b_qkv_c = (const float*)d_in[4];
  const float* w_up    = (const float*)d_in[5];
  const float* b_up    = (const float*)d_in[6];
  const float* w_qkv_t = (const float*)d_in[7];
  const float* b_qkv_t = (const float*)d_in[8];
  const float* w_dw    = (const float*)d_in[9];
  const float* g_dw    = (const float*)d_in[10];
  const float* be_dw   = (const float*)d_in[11];
  const float* w_pw    = (const float*)d_in[12];
  const float* g_pw    = (const float*)d_in[13];
  const float* be_pw   = (const float*)d_in[14];
  float* out = (float*)d_out;

  float* ws    = (float*)d_ws;
  float* xd    = ws;                       // 492032 = 4*128*961
  float* o1    = xd + 492032;              // 492032
  int*   topk  = (int*)(o1 + 492032);      // 15360 = 4*16*240
  float* yacc  = (float*)(topk + 15360);   // 984064 = 4*64*62*62
  float* z1    = yacc + 984064;            // 984064
  float* z2    = z1 + 984064;              // 984064
  float* stats = z2 + 984064;              // 256
  float* par   = stats + 256;              // 256

  // disjoint-lifetime aliases:
  // k_down partials (pre-attn): o1, yacc(x2), z1(x2), z2(x2), xd -- all dead until combine
  float*  rowstat = z1;                    // 4*16*961 floats (post-combine)
  float*  coarse  = z1 + 61504;            // 4*16*961 floats
  float4* o2      = (float4*)z2;           // 4*16*960 float4
  int*    coordg  = (int*)(z2 + 245760);   // 61440 ints

  k_zero<<<1, 256, 0, stream>>>(stats, 256);
  k_down<<<1024, 256, 0, stream>>>(x, w_down,
                                   o1, yacc, yacc + 492032, z1, z1 + 492032,
                                   z2, z2 + 492032, xd);
  k_combine<<<(XDSZ + 255) / 256, 256, 0, stream>>>(o1, yacc, yacc + 492032, z1,
                                                    z1 + 492032, z2, z2 + 492032,
                                                    b_down, xd);
  k_attn1<<<2048, 256, 0, stream>>>(xd, w_qkv_c, b_qkv_c, o1, rowstat);
  k_coarse<<<2048, 256, 0, stream>>>(xd, w_qkv_c, b_qkv_c, rowstat, coarse);
  k_topk<<<64, 256, 0, stream>>>(coarse, topk);
  k_upconv<<<1024, 256, 0, stream>>>(o1, w_up, b_up, yacc);
  k_attn2<<<960, 256, 0, stream>>>(yacc, w_qkv_t, b_qkv_t, topk, o2, coordg);
  k_scatter<<<(64 * N2 + 255) / 256, 256, 0, stream>>>(yacc, o2, coordg);
  k_dwconv<<<(64 * NPIX + 255) / 256, 256, 0, stream>>>(yacc, w_dw, z1);
  k_stats<<<1024, 256, 0, stream>>>(z1, stats);
  k_bnparam<<<1, 64, 0, stream>>>(stats, g_dw, be_dw, par);
  k_pwconv<<<61 * 16, 256, 0, stream>>>(z1, w_pw, par, z2);
  k_stats<<<1024, 256, 0, stream>>>(z2, stats + 128);
  k_bnparam<<<1, 64, 0, stream>>>(stats + 128, g_pw, be_pw, par + 128);
  k_final<<<(64 * NPIX + 255) / 256, 256, 0, stream>>>(z2, par + 128, out);
}

// Round 16
// 317.336 us; speedup vs baseline: 1.0872x; 1.0872x over previous
//
#include <hip/hip_runtime.h>
#include <math.h>

#define N1 961
#define N2 960
#define KF 240
#define HW2 3844   // 62*62
#define NPIX 15376 // 4*62*62
#define XDSZ 492032 // 4*128*961
#define L2E 1.44269504f

typedef float v2f __attribute__((ext_vector_type(2)));

__global__ void k_zero(float* p, int n) {
  int i = blockIdx.x * 256 + threadIdx.x;
  if (i < n) p[i] = 0.f;
}

// down conv v4: 2x2 px x 4 co per thread, K-split x8 (1024 blocks = 4/CU).
__global__ __launch_bounds__(256) void k_down(const float* __restrict__ x,
                                              const float* __restrict__ w,
                                              float* __restrict__ p0, float* __restrict__ p1,
                                              float* __restrict__ p2, float* __restrict__ p3,
                                              float* __restrict__ p4, float* __restrict__ p5,
                                              float* __restrict__ p6, float* __restrict__ p7) {
  __shared__ float iS[4][18][72];
  __shared__ float wS[4][16][16];  // [ci][tap][co16]
  int tid = threadIdx.x;
  int bid = blockIdx.x;
  int kchunk = bid & 7;
  int rowtile = (bid >> 3) & 3;
  int cog = (bid >> 5) & 7;
  int b = bid >> 8;
  int r0 = rowtile * 8;
  int wv = tid >> 6, lane = tid & 63;
  int pc = lane & 15, pr = lane >> 4;
  float acc[4][4];  // [px][co]
  #pragma unroll
  for (int i = 0; i < 4; i++)
    #pragma unroll
    for (int j = 0; j < 4; j++) acc[i][j] = 0.f;
  const float* xb = x + (size_t)b * 64 * 4096;
  for (int sub = 0; sub < 2; sub++) {
    int cibase = kchunk * 8 + sub * 4;
    __syncthreads();
    for (int e = tid; e < 4 * 18 * 66; e += 256) {
      int dx = e % 66; int t = e / 66;
      int dy = t % 18; int ci = t / 18;
      int iy = 2 * r0 + dy;
      iS[ci][dy][dx] = (dx < 64 && iy < 64)
                           ? xb[(size_t)(cibase + ci) * 4096 + iy * 64 + dx] : 0.f;
    }
    for (int e = tid; e < 1024; e += 256) {
      int co = e & 15, tap = (e >> 4) & 15, ci = e >> 8;
      wS[ci][tap][co] = w[(size_t)(cog * 16 + co) * 1024 + (cibase + ci) * 16 + tap];
    }
    __syncthreads();
    #pragma unroll
    for (int ci = 0; ci < 4; ci++) {
      float xr[6][6];
      #pragma unroll
      for (int rr = 0; rr < 6; rr++)
        #pragma unroll
        for (int jj = 0; jj < 3; jj++) {
          float2 v2 = *(const float2*)&iS[ci][4 * pr + rr][4 * pc + 2 * jj];
          xr[rr][2 * jj] = v2.x; xr[rr][2 * jj + 1] = v2.y;
        }
      #pragma unroll
      for (int ky = 0; ky < 4; ky++)
        #pragma unroll
        for (int kx = 0; kx < 4; kx++) {
          float4 wq = *(const float4*)&wS[ci][ky * 4 + kx][wv * 4];  // broadcast
          #pragma unroll
          for (int dy2 = 0; dy2 < 2; dy2++)
            #pragma unroll
            for (int dx2 = 0; dx2 < 2; dx2++) {
              float xv = xr[2 * dy2 + ky][2 * dx2 + kx];
              int px = dy2 * 2 + dx2;
              acc[px][0] += wq.x * xv; acc[px][1] += wq.y * xv;
              acc[px][2] += wq.z * xv; acc[px][3] += wq.w * xv;
            }
        }
    }
  }
  float* parts[8] = {p0, p1, p2, p3, p4, p5, p6, p7};
  float* xo = parts[kchunk] + (size_t)b * 128 * N1;
  #pragma unroll
  for (int dy2 = 0; dy2 < 2; dy2++) {
    int r = r0 + 2 * pr + dy2;
    if (r >= 31) continue;
    #pragma unroll
    for (int dx2 = 0; dx2 < 2; dx2++) {
      int c = 2 * pc + dx2;
      if (c >= 31) continue;
      #pragma unroll
      for (int cc = 0; cc < 4; cc++)
        xo[(size_t)(cog * 16 + wv * 4 + cc) * N1 + r * 31 + c] = acc[dy2 * 2 + dx2][cc];
    }
  }
}

// combine 7 K-partials + xd(8th partial) + bias -> xd
__global__ __launch_bounds__(256) void k_combine(const float* __restrict__ p0,
                                                 const float* __restrict__ p1,
                                                 const float* __restrict__ p2,
                                                 const float* __restrict__ p3,
                                                 const float* __restrict__ p4,
                                                 const float* __restrict__ p5,
                                                 const float* __restrict__ p6,
                                                 const float* __restrict__ bias,
                                                 float* __restrict__ xd) {
  int i = blockIdx.x * 256 + threadIdx.x;
  if (i >= XDSZ) return;
  int co = (i / N1) & 127;
  float s = ((p0[i] + p1[i]) + (p2[i] + p3[i])) + ((p4[i] + p5[i]) + (p6[i] + xd[i]));
  xd[i] = bias[co] + s;
}

#define QKV_EXPR(off) make_float4( \
    t0 * Ws[(off)] + t1 * Ws[12 + (off)] + t2 * Ws[24 + (off)] + t3 * Ws[36 + (off)] + Bs[(off)], \
    t0 * Ws[(off)+1] + t1 * Ws[12 + (off)+1] + t2 * Ws[24 + (off)+1] + t3 * Ws[36 + (off)+1] + Bs[(off)+1], \
    t0 * Ws[(off)+2] + t1 * Ws[12 + (off)+2] + t2 * Ws[24 + (off)+2] + t3 * Ws[36 + (off)+2] + Bs[(off)+2], \
    t0 * Ws[(off)+3] + t1 * Ws[12 + (off)+3] + t2 * Ws[24 + (off)+3] + t3 * Ws[36 + (off)+3] + Bs[(off)+3])

// load qkv weights; q-columns (0..3) pre-scaled by log2(e) so exp(s) == exp2(k.q')
#define LOAD_W_SCALED(wqkv, bqkv) do { \
    if (tid < 48) { float wv_ = (wqkv)[tid]; if ((tid % 12) < 4) wv_ *= L2E; Ws[tid] = wv_; } \
    if (tid < 12) { float bv_ = (bqkv)[tid]; if (tid < 4) bv_ *= L2E; Bs[tid] = bv_; } \
  } while (0)

// attention 1: 2 rows/thread (packed v2f), 4-way m-split. grid = 128 bg x 8 chunks.
__global__ __launch_bounds__(256) void k_attn1(const float* __restrict__ xd,
                                               const float* __restrict__ wqkv,
                                               const float* __restrict__ bqkv,
                                               float* __restrict__ o1,
                                               float* __restrict__ rowstat) {
  __shared__ float4 qvv[2 * N1];
  __shared__ float Ws[48], Bs[12];
  int tid = threadIdx.x;
  int chunk = blockIdx.x & 7;
  int bg = blockIdx.x >> 3;
  int b = bg >> 5, g = bg & 31;
  LOAD_W_SCALED(wqkv, bqkv);
  __syncthreads();
  const float* xp0 = xd + (size_t)(b * 128 + g * 4) * N1;
  for (int nn = tid; nn < N1; nn += 256) {
    float t0 = xp0[nn], t1 = xp0[N1 + nn], t2 = xp0[2 * N1 + nn], t3 = xp0[3 * N1 + nn];
    qvv[2 * nn]     = QKV_EXPR(0);
    qvv[2 * nn + 1] = QKV_EXPR(8);
  }
  __syncthreads();
  int wv = tid >> 6, lane = tid & 63;
  int q4 = lane >> 4;
  int n0 = chunk * 128 + wv * 32 + (lane & 15);
  if (n0 >= N1) return;  // all quarter-partners share n0 -> exit together
  int n1 = n0 + 16;
  bool v1 = n1 < N1;
  int n1c = v1 ? n1 : n0;
  float t0 = xp0[n0], t1 = xp0[N1 + n0], t2 = xp0[2 * N1 + n0], t3 = xp0[3 * N1 + n0];
  float4 kr0 = QKV_EXPR(4);
  t0 = xp0[n1c]; t1 = xp0[N1 + n1c]; t2 = xp0[2 * N1 + n1c]; t3 = xp0[3 * N1 + n1c];
  float4 kr1 = QKV_EXPR(4);
  v2f krx = {kr0.x, kr1.x}, kry = {kr0.y, kr1.y};
  v2f krz = {kr0.z, kr1.z}, krw = {kr0.w, kr1.w};
  int ns = q4 * 241;
  int ne = (ns + 241 < N1) ? ns + 241 : N1;
  v2f sum = {0.f, 0.f}, A0 = {0.f, 0.f}, A1 = {0.f, 0.f}, A2 = {0.f, 0.f}, A3 = {0.f, 0.f};
  #pragma unroll 4
  for (int m = ns; m < ne; m++) {
    float4 q = qvv[2 * m];
    float4 v = qvv[2 * m + 1];
    v2f s = krx * q.x + kry * q.y + krz * q.z + krw * q.w;  // v_pk_fma_f32
    v2f e;
    e.x = __builtin_amdgcn_exp2f(s.x);
    e.y = __builtin_amdgcn_exp2f(s.y);
    sum += e;
    A0 += e * v.x; A1 += e * v.y; A2 += e * v.z; A3 += e * v.w;
  }
  #pragma unroll
  for (int off = 16; off <= 32; off <<= 1) {
    sum.x += __shfl_xor(sum.x, off, 64); sum.y += __shfl_xor(sum.y, off, 64);
    A0.x += __shfl_xor(A0.x, off, 64);   A0.y += __shfl_xor(A0.y, off, 64);
    A1.x += __shfl_xor(A1.x, off, 64);   A1.y += __shfl_xor(A1.y, off, 64);
    A2.x += __shfl_xor(A2.x, off, 64);   A2.y += __shfl_xor(A2.y, off, 64);
    A3.x += __shfl_xor(A3.x, off, 64);   A3.y += __shfl_xor(A3.y, off, 64);
  }
  if (q4 != 0) return;
  float* o1p = o1 + (size_t)(b * 128 + g * 4) * N1;
  float inv0 = 1.0f / sum.x;
  o1p[n0] = A0.x * inv0;
  o1p[N1 + n0] = A1.x * inv0;
  o1p[2 * N1 + n0] = A2.x * inv0;
  o1p[3 * N1 + n0] = A3.x * inv0;
  if (g < 16) rowstat[(size_t)(b * 16 + g) * N1 + n0] = inv0;
  if (v1) {
    float inv1 = 1.0f / sum.y;
    o1p[n1] = A0.y * inv1;
    o1p[N1 + n1] = A1.y * inv1;
    o1p[2 * N1 + n1] = A2.y * inv1;
    o1p[3 * N1 + n1] = A3.y * inv1;
    if (g < 16) rowstat[(size_t)(b * 16 + g) * N1 + n1] = inv1;
  }
}

// coarse: 2 cols/thread (packed v2f), 8-way n-split. grid = 64 bg x 16 chunks.
__global__ __launch_bounds__(256) void k_coarse(const float* __restrict__ xd,
                                                const float* __restrict__ wqkv,
                                                const float* __restrict__ bqkv,
                                                const float* __restrict__ rowstat,
                                                float* __restrict__ coarse) {
  __shared__ float4 kS[N1];
  __shared__ float rs[N1];
  __shared__ float Ws[48], Bs[12];
  int tid = threadIdx.x;
  int chunk = blockIdx.x & 15;
  int bg = blockIdx.x >> 4;
  int b = bg >> 4, g = bg & 15;
  LOAD_W_SCALED(wqkv, bqkv);
  __syncthreads();
  const float* xp0 = xd + (size_t)(b * 128 + g * 4) * N1;
  const float* rp = rowstat + (size_t)(b * 16 + g) * N1;
  for (int nn = tid; nn < N1; nn += 256) {
    float t0 = xp0[nn], t1 = xp0[N1 + nn], t2 = xp0[2 * N1 + nn], t3 = xp0[3 * N1 + nn];
    kS[nn] = QKV_EXPR(4);
    rs[nn] = rp[nn];
  }
  __syncthreads();
  int wv = tid >> 6, lane = tid & 63;
  int oc = lane >> 3;
  int m0 = chunk * 64 + wv * 16 + (lane & 7);
  if (m0 >= N1) return;  // octant partners share m0 -> exit together
  int m1 = m0 + 8;
  bool v1 = m1 < N1;
  int m1c = v1 ? m1 : m0;
  float t0 = xp0[m0], t1 = xp0[N1 + m0], t2 = xp0[2 * N1 + m0], t3 = xp0[3 * N1 + m0];
  float4 q0 = QKV_EXPR(0);  // pre-scaled by log2e
  t0 = xp0[m1c]; t1 = xp0[N1 + m1c]; t2 = xp0[2 * N1 + m1c]; t3 = xp0[3 * N1 + m1c];
  float4 q1 = QKV_EXPR(0);
  v2f qx = {q0.x, q1.x}, qy = {q0.y, q1.y}, qz = {q0.z, q1.z}, qw = {q0.w, q1.w};
  int ns = oc * 121;
  int ne = (ns + 121 < N1) ? ns + 121 : N1;
  v2f c = {0.f, 0.f};
  #pragma unroll 4
  for (int n = ns; n < ne; n++) {
    float4 k = kS[n];
    float r = rs[n];
    v2f s = qx * k.x + qy * k.y + qz * k.z + qw * k.w;
    v2f e;
    e.x = __builtin_amdgcn_exp2f(s.x);
    e.y = __builtin_amdgcn_exp2f(s.y);
    c += e * r;
  }
  #pragma unroll
  for (int off = 8; off <= 32; off <<= 1) {
    c.x += __shfl_xor(c.x, off, 64);
    c.y += __shfl_xor(c.y, off, 64);
  }
  if (oc != 0) return;
  coarse[(size_t)(b * 16 + g) * N1 + m0] = c.x;
  if (v1) coarse[(size_t)(b * 16 + g) * N1 + m1] = c.y;
}

// top-240 per (b,g<16): bitonic over 1024 packed keys
__global__ __launch_bounds__(256) void k_topk(const float* __restrict__ coarse,
                                              int* __restrict__ topk) {
  __shared__ unsigned long long keys[1024];
  int tid = threadIdx.x;
  int bg = blockIdx.x;
  const float* cp = coarse + (size_t)bg * N1;
  for (int i = tid; i < 1024; i += 256) {
    unsigned long long key = 0ull;
    if (i < N1) {
      unsigned fb = __float_as_uint(cp[i]);
      key = ((unsigned long long)fb << 32) | (unsigned)(N1 - 1 - i);
    }
    keys[i] = key;
  }
  __syncthreads();
  for (int k2 = 2; k2 <= 1024; k2 <<= 1) {
    for (int j = k2 >> 1; j > 0; j >>= 1) {
      for (int i = tid; i < 1024; i += 256) {
        int ixj = i ^ j;
        if (ixj > i) {
          unsigned long long a = keys[i], bb = keys[ixj];
          bool up = ((i & k2) == 0);
          if ((a > bb) == up) { keys[i] = bb; keys[ixj] = a; }
        }
      }
      __syncthreads();
    }
  }
  if (tid < KF) {
    unsigned long long key = keys[1023 - tid];
    topk[(size_t)bg * KF + tid] = (N1 - 1) - (int)(unsigned)(key & 0xffffffffull);
  }
}

// transposed conv, per-parity: o1(4,128,31,31) -> yacc = 2*coarse_out (4,64,62,62)
__global__ __launch_bounds__(256) void k_upconv(const float* __restrict__ o1,
                                                const float* __restrict__ w,
                                                const float* __restrict__ bias,
                                                float* __restrict__ yacc) {
  __shared__ float iS[16][9][12];
  __shared__ float wS[16][4][16];  // [ci][tap][co16]
  int tid = threadIdx.x;
  int bid = blockIdx.x;
  int b = bid >> 8;
  int cog = (bid >> 6) & 3;
  int par = (bid >> 4) & 3;
  int py = par >> 1, px = par & 1;
  int tile = bid & 15;
  int r0 = (tile >> 2) * 8, c0 = (tile & 3) * 8;
  int wv = tid >> 6, lane = tid & 63;
  int pr = lane >> 3, pc = lane & 7;
  int cobase = cog * 16 + wv * 4;
  int wo[4];
  #pragma unroll
  for (int t = 0; t < 4; t++) {
    int a = t >> 1, d = t & 1;
    wo[t] = (3 - (py + 2 * a)) * 4 + (3 - (px + 2 * d));
  }
  float acc[4] = {0.f, 0.f, 0.f, 0.f};
  const float* ob = o1 + (size_t)b * 128 * N1;
  for (int ch = 0; ch < 8; ch++) {
    __syncthreads();
    for (int e = tid; e < 16 * 81; e += 256) {
      int dx = e % 9; int t = e / 9;
      int dy = t % 9; int ci = t / 9;
      int iy = r0 + py - 1 + dy, ix = c0 + px - 1 + dx;
      float v = 0.f;
      if (iy >= 0 && iy < 31 && ix >= 0 && ix < 31)
        v = ob[(size_t)(ch * 16 + ci) * N1 + iy * 31 + ix];
      iS[ci][dy][dx] = v;
    }
    for (int e = tid; e < 1024; e += 256) {
      int co = e & 15, tap = (e >> 4) & 3, ci = e >> 6;
      wS[ci][tap][co] = w[(size_t)(ch * 16 + ci) * 1024 + (cog * 16 + co) * 16 + wo[tap]];
    }
    __syncthreads();
    #pragma unroll
    for (int ci = 0; ci < 16; ci++) {
      float xr[2][2];
      #pragma unroll
      for (int a = 0; a < 2; a++) {
        xr[a][0] = iS[ci][pr + a][pc];
        xr[a][1] = iS[ci][pr + a][pc + 1];
      }
      #pragma unroll
      for (int t = 0; t < 4; t++) {
        float4 wq = *(const float4*)&wS[ci][t][wv * 4];  // broadcast
        float xv = xr[t >> 1][t & 1];
        acc[0] += wq.x * xv; acc[1] += wq.y * xv;
        acc[2] += wq.z * xv; acc[3] += wq.w * xv;
      }
    }
  }
  int r = r0 + pr, c = c0 + pc;
  if (r >= 31 || c >= 31) return;
  int y = 2 * r + py, xx = 2 * c + px;
  #pragma unroll
  for (int cc = 0; cc < 4; cc++) {
    int co = cobase + cc;
    yacc[(size_t)(b * 64 + co) * HW2 + y * 62 + xx] = 2.0f * (acc[cc] + bias[co]);
  }
}

// attention 2: 2 rows/thread (packed v2f), 4-way m-split. grid = 64 bg x 8 chunks.
__global__ __launch_bounds__(256) void k_attn2(const float* __restrict__ yacc,
                                               const float* __restrict__ wqkv,
                                               const float* __restrict__ bqkv,
                                               const int* __restrict__ topk,
                                               float4* __restrict__ o2,
                                               int* __restrict__ coordg) {
  __shared__ float4 qvv[2 * N2];
  __shared__ float Ws[48], Bs[12];
  int tid = threadIdx.x;
  int chunk = blockIdx.x & 7;
  int bg = blockIdx.x >> 3;
  int b = bg >> 4, g = bg & 15;
  LOAD_W_SCALED(wqkv, bqkv);
  __syncthreads();
  const float* yp0 = yacc + (size_t)(b * 64 + g * 4) * HW2;
  const int* ip = topk + (size_t)bg * KF;
  for (int nn = tid; nn < N2; nn += 256) {
    int tt = nn >> 2, i = (nn >> 1) & 1, j = nn & 1;
    int p = ip[tt];
    int ph = p / 31, pw = p - ph * 31;
    int cc = (2 * ph + i) * 62 + (2 * pw + j);
    float t0 = 0.5f * yp0[cc], t1 = 0.5f * yp0[HW2 + cc];
    float t2 = 0.5f * yp0[2 * HW2 + cc], t3 = 0.5f * yp0[3 * HW2 + cc];
    qvv[2 * nn]     = QKV_EXPR(0);
    qvv[2 * nn + 1] = QKV_EXPR(8);
  }
  __syncthreads();
  int wv = tid >> 6, lane = tid & 63;
  int q4 = lane >> 4;
  int n0 = chunk * 128 + wv * 32 + (lane & 15);
  if (n0 >= N2) return;
  int n1 = n0 + 16;
  bool v1 = n1 < N2;
  int n1c = v1 ? n1 : n0;
  int tt = n0 >> 2, i = (n0 >> 1) & 1, j = n0 & 1;
  int p = ip[tt];
  int ph = p / 31, pw = p - ph * 31;
  int cc0 = (2 * ph + i) * 62 + (2 * pw + j);
  float t0 = 0.5f * yp0[cc0], t1 = 0.5f * yp0[HW2 + cc0];
  float t2 = 0.5f * yp0[2 * HW2 + cc0], t3 = 0.5f * yp0[3 * HW2 + cc0];
  float4 kr0 = QKV_EXPR(4);
  tt = n1c >> 2; i = (n1c >> 1) & 1; j = n1c & 1;
  p = ip[tt];
  ph = p / 31; pw = p - ph * 31;
  int cc1 = (2 * ph + i) * 62 + (2 * pw + j);
  t0 = 0.5f * yp0[cc1]; t1 = 0.5f * yp0[HW2 + cc1];
  t2 = 0.5f * yp0[2 * HW2 + cc1]; t3 = 0.5f * yp0[3 * HW2 + cc1];
  float4 kr1 = QKV_EXPR(4);
  v2f krx = {kr0.x, kr1.x}, kry = {kr0.y, kr1.y};
  v2f krz = {kr0.z, kr1.z}, krw = {kr0.w, kr1.w};
  int ns = q4 * 240;
  int ne = ns + 240;
  v2f sum = {0.f, 0.f}, A0 = {0.f, 0.f}, A1 = {0.f, 0.f}, A2 = {0.f, 0.f}, A3 = {0.f, 0.f};
  #pragma unroll 4
  for (int m = ns; m < ne; m++) {
    float4 q = qvv[2 * m];
    float4 v = qvv[2 * m + 1];
    v2f s = krx * q.x + kry * q.y + krz * q.z + krw * q.w;
    v2f e;
    e.x = __builtin_amdgcn_exp2f(s.x);
    e.y = __builtin_amdgcn_exp2f(s.y);
    sum += e;
    A0 += e * v.x; A1 += e * v.y; A2 += e * v.z; A3 += e * v.w;
  }
  #pragma unroll
  for (int off = 16; off <= 32; off <<= 1) {
    sum.x += __shfl_xor(sum.x, off, 64); sum.y += __shfl_xor(sum.y, off, 64);
    A0.x += __shfl_xor(A0.x, off, 64);   A0.y += __shfl_xor(A0.y, off, 64);
    A1.x += __shfl_xor(A1.x, off, 64);   A1.y += __shfl_xor(A1.y, off, 64);
    A2.x += __shfl_xor(A2.x, off, 64);   A2.y += __shfl_xor(A2.y, off, 64);
    A3.x += __shfl_xor(A3.x, off, 64);   A3.y += __shfl_xor(A3.y, off, 64);
  }
  if (q4 != 0) return;
  float inv0 = 1.0f / sum.x;
  size_t oi = (size_t)bg * N2 + n0;
  o2[oi] = make_float4(A0.x * inv0, A1.x * inv0, A2.x * inv0, A3.x * inv0);
  coordg[oi] = cc0;
  if (v1) {
    float inv1 = 1.0f / sum.y;
    oi = (size_t)bg * N2 + n1;
    o2[oi] = make_float4(A0.y * inv1, A1.y * inv1, A2.y * inv1, A3.y * inv1);
    coordg[oi] = cc1;
  }
}

// scatter-add attn2 output into yacc (disjoint targets)
__global__ __launch_bounds__(256) void k_scatter(float* __restrict__ yacc,
                                                 const float4* __restrict__ o2,
                                                 const int* __restrict__ coordg) {
  int idx = blockIdx.x * 256 + threadIdx.x;
  if (idx >= 64 * N2) return;
  int bg = idx / N2;
  int b = bg >> 4, g = bg & 15;
  float4 o = o2[idx];
  int cc = coordg[idx];
  float* yp0 = yacc + (size_t)(b * 64 + g * 4) * HW2;
  yp0[cc] += o.x;
  yp0[HW2 + cc] += o.y;
  yp0[2 * HW2 + cc] += o.z;
  yp0[3 * HW2 + cc] += o.w;
}

// depthwise 3x3, pad 1
__global__ __launch_bounds__(256) void k_dwconv(const float* __restrict__ yin,
                                                const float* __restrict__ w,
                                                float* __restrict__ z1) {
  int idx = blockIdx.x * 256 + threadIdx.x;
  if (idx >= 64 * NPIX) return;
  int x = idx % 62; int t = idx / 62;
  int y = t % 62; t /= 62;
  int c = t % 64;
  int plane = idx / HW2;
  const float* yp = yin + (size_t)plane * HW2;
  const float* wp = w + c * 9;
  float acc = 0.f;
  #pragma unroll
  for (int ky = 0; ky < 3; ky++) {
    int yy = y + ky - 1;
    if (yy < 0 || yy > 61) continue;
    #pragma unroll
    for (int kx = 0; kx < 3; kx++) {
      int xx = x + kx - 1;
      if (xx < 0 || xx > 61) continue;
      acc += yp[yy * 62 + xx] * wp[ky * 3 + kx];
    }
  }
  z1[idx] = acc;
}

__device__ __forceinline__ float wave_sum(float x) {
  #pragma unroll
  for (int off = 32; off > 0; off >>= 1) x += __shfl_xor(x, off, 64);
  return x;
}

// per-channel sum/sumsq; grid 1024 = c(64) x b(4) x seg(4: 961 px each)
__global__ __launch_bounds__(256) void k_stats(const float* __restrict__ buf,
                                               float* __restrict__ stats) {
  __shared__ float red[8];
  int bid = blockIdx.x;
  int seg = bid & 3;
  int b = (bid >> 2) & 3;
  int c = bid >> 4;
  const float* p = buf + (size_t)(b * 64 + c) * HW2;
  int i0 = seg * 961;
  float s = 0.f, s2 = 0.f;
  for (int i = i0 + threadIdx.x; i < i0 + 961; i += 256) {
    float z = p[i]; s += z; s2 += z * z;
  }
  s = wave_sum(s); s2 = wave_sum(s2);
  int wave = threadIdx.x >> 6, lane = threadIdx.x & 63;
  if (lane == 0) { red[wave] = s; red[4 + wave] = s2; }
  __syncthreads();
  if (threadIdx.x == 0) {
    atomicAdd(&stats[c], red[0] + red[1] + red[2] + red[3]);
    atomicAdd(&stats[64 + c], red[4] + red[5] + red[6] + red[7]);
  }
}

__global__ void k_bnparam(const float* __restrict__ stats, const float* __restrict__ gamma,
                          const float* __restrict__ beta, float* __restrict__ par) {
  int c = threadIdx.x;
  if (c < 64) {
    float m = stats[c] * (1.0f / NPIX);
    float v = stats[64 + c] * (1.0f / NPIX) - m * m;
    float a = gamma[c] * rsqrtf(v + 1e-5f);
    par[c] = a; par[64 + c] = beta[c] - m * a;
  }
}

// pointwise 1x1, co-split x16 (4 co/block): grid = pixblocks(61) x cog(16)
__global__ __launch_bounds__(256) void k_pwconv(const float* __restrict__ z1,
                                                const float* __restrict__ wpw,
                                                const float* __restrict__ par,
                                                float* __restrict__ z2) {
  __shared__ float w[4 * 64];
  __shared__ float aa[64], cb[64];
  int tid = threadIdx.x;
  int cog = blockIdx.x & 15;
  int pb = blockIdx.x >> 4;
  if (tid < 64) { aa[tid] = par[tid]; cb[tid] = par[64 + tid]; }
  for (int i = tid; i < 256; i += 256) w[i] = wpw[cog * 256 + i];
  __syncthreads();
  int pix = pb * 256 + tid;
  if (pix >= NPIX) return;
  int b = pix / HW2, p = pix - b * HW2;
  float h[64];
  #pragma unroll
  for (int ci = 0; ci < 64; ci++) {
    float z = z1[(size_t)(b * 64 + ci) * HW2 + p];
    z = aa[ci] * z + cb[ci];
    h[ci] = fminf(fmaxf(z, 0.f), 6.f);
  }
  #pragma unroll
  for (int cc = 0; cc < 4; cc++) {
    float acc = 0.f;
    #pragma unroll
    for (int ci = 0; ci < 64; ci++) acc += h[ci] * w[cc * 64 + ci];
    z2[(size_t)(b * 64 + cog * 4 + cc) * HW2 + p] = acc;
  }
}

__global__ __launch_bounds__(256) void k_final(const float* __restrict__ z2,
                                               const float* __restrict__ par,
                                               float* __restrict__ out) {
  int idx = blockIdx.x * 256 + threadIdx.x;
  if (idx >= 64 * NPIX) return;
  int c = (idx / HW2) & 63;
  float z = par[c] * z2[idx] + par[64 + c];
  out[idx] = fminf(fmaxf(z, 0.f), 6.f);
}

extern "C" void kernel_launch(void* const* d_in, const int* in_sizes, int n_in,
                              void* d_out, int out_size, void* d_ws, size_t ws_size,
                              hipStream_t stream) {
  const float* x       = (const float*)d_in[0];
  const float* w_down  = (const float*)d_in[1];
  const float* b_down  = (const float*)d_in[2];
  const float* w_qkv_c = (const float*)d_in[3];
  const float* b_qkv_c = (const float*)d_in[4];
  const float* w_up    = (const float*)d_in[5];
  const float* b_up    = (const float*)d_in[6];
  const float* w_qkv_t = (const float*)d_in[7];
  const float* b_qkv_t = (const float*)d_in[8];
  const float* w_dw    = (const float*)d_in[9];
  const float* g_dw    = (const float*)d_in[10];
  const float* be_dw   = (const float*)d_in[11];
  const float* w_pw    = (const float*)d_in[12];
  const float* g_pw    = (const float*)d_in[13];
  const float* be_pw   = (const float*)d_in[14];
  float* out = (float*)d_out;

  float* ws    = (float*)d_ws;
  float* xd    = ws;                       // 492032 = 4*128*961
  float* o1    = xd + 492032;              // 492032
  int*   topk  = (int*)(o1 + 492032);      // 15360 = 4*16*240
  float* yacc  = (float*)(topk + 15360);   // 984064 = 4*64*62*62
  float* z1    = yacc + 984064;            // 984064
  float* z2    = z1 + 984064;              // 984064
  float* stats = z2 + 984064;              // 256
  float* par   = stats + 256;              // 256

  // disjoint-lifetime aliases:
  // k_down partials (pre-attn): o1, yacc(x2), z1(x2), z2(x2), xd -- all dead until combine
  float*  rowstat = z1;                    // 4*16*961 floats (post-combine)
  float*  coarse  = z1 + 61504;            // 4*16*961 floats
  float4* o2      = (float4*)z2;           // 4*16*960 float4
  int*    coordg  = (int*)(z2 + 245760);   // 61440 ints

  k_zero<<<1, 256, 0, stream>>>(stats, 256);
  k_down<<<1024, 256, 0, stream>>>(x, w_down,
                                   o1, yacc, yacc + 492032, z1, z1 + 492032,
                                   z2, z2 + 492032, xd);
  k_combine<<<(XDSZ + 255) / 256, 256, 0, stream>>>(o1, yacc, yacc + 492032, z1,
                                                    z1 + 492032, z2, z2 + 492032,
                                                    b_down, xd);
  k_attn1<<<1024, 256, 0, stream>>>(xd, w_qkv_c, b_qkv_c, o1, rowstat);
  k_coarse<<<1024, 256, 0, stream>>>(xd, w_qkv_c, b_qkv_c, rowstat, coarse);
  k_topk<<<64, 256, 0, stream>>>(coarse, topk);
  k_upconv<<<1024, 256, 0, stream>>>(o1, w_up, b_up, yacc);
  k_attn2<<<512, 256, 0, stream>>>(yacc, w_qkv_t, b_qkv_t, topk, o2, coordg);
  k_scatter<<<(64 * N2 + 255) / 256, 256, 0, stream>>>(yacc, o2, coordg);
  k_dwconv<<<(64 * NPIX + 255) / 256, 256, 0, stream>>>(yacc, w_dw, z1);
  k_stats<<<1024, 256, 0, stream>>>(z1, stats);
  k_bnparam<<<1, 64, 0, stream>>>(stats, g_dw, be_dw, par);
  k_pwconv<<<61 * 16, 256, 0, stream>>>(z1, w_pw, par, z2);
  k_stats<<<1024, 256, 0, stream>>>(z2, stats + 128);
  k_bnparam<<<1, 64, 0, stream>>>(stats + 128, g_pw, be_pw, par + 128);
  k_final<<<(64 * NPIX + 255) / 256, 256, 0, stream>>>(z2, par + 128, out);
}